// Round 12
// baseline (2698.742 us; speedup 1.0000x reference)
//
#include <hip/hip_runtime.h>

// SymHQLinear: out[8192,4096] = x @ W^T; W[4096,4096] dequantized from
// codebook[4096,8] + per-row scales + packed sign bits.
// Strategy: per-row symmetric i8 quantization of X and W, mfma_i32_16x16x64_i8
// GEMM, fp32 epilogue scales.  R12: single read-block per tile + wave-group
// STAGGER (wm=0 waves compute quad0 first, wm=1 quad1 first) so each SIMD's
// two waves alternate LDS-read vs MFMA instead of bursting in lockstep.
#define M_ 8192   // TOKENS
#define N_ 4096   // OUT
#define K_ 4096   // IN

typedef float f32x4 __attribute__((ext_vector_type(4)));
typedef int   i32x4 __attribute__((ext_vector_type(4)));

// ---------------------------------------------------------------------------
// Kernel 1 (fused prep): blocks [0, 4096): W row -> dequant, row-max, i8 + sw
//                        blocks [4096, 12288): X row -> row-max, i8 + sx
// ---------------------------------------------------------------------------
__device__ __forceinline__ unsigned pack4(const float* v, float inv) {
  unsigned r = 0;
#pragma unroll
  for (int j = 0; j < 4; ++j) {
    int q = (int)rintf(v[j] * inv);
    q = q < -127 ? -127 : (q > 127 ? 127 : q);
    r |= ((unsigned)(q & 0xff)) << (8 * j);
  }
  return r;
}

__global__ __launch_bounds__(256) void prep_kernel(
    const float* __restrict__ x, const float* __restrict__ cb,
    const float* __restrict__ scales, const int* __restrict__ idx,
    const int* __restrict__ signs,
    signed char* __restrict__ Wq, signed char* __restrict__ Xq,
    float* __restrict__ sw, float* __restrict__ sx)
{
  __shared__ float wred[4];
  const int b = blockIdx.x, t = threadIdx.x;

  if (b < N_) {
    // ---- W row b: 512 groups; thread handles groups t and t+256 ----
    const float s = scales[b];
    const int g0 = b * 512 + t, g1 = g0 + 256;
    const int c0 = idx[g0], c1 = idx[g1];
    const int sb0 = signs[g0], sb1 = signs[g1];
    const float* cv0 = cb + c0 * 8;
    const float* cv1 = cb + c1 * 8;
    float v[16];
    float mx = 0.f;
#pragma unroll
    for (int j = 0; j < 8; ++j) {
      float a = cv0[j] * s;
      if (!((sb0 >> (7 - j)) & 1)) a = -a;
      v[j] = a; mx = fmaxf(mx, fabsf(a));
    }
#pragma unroll
    for (int j = 0; j < 8; ++j) {
      float a = cv1[j] * s;
      if (!((sb1 >> (7 - j)) & 1)) a = -a;
      v[8 + j] = a; mx = fmaxf(mx, fabsf(a));
    }
#pragma unroll
    for (int off = 1; off < 64; off <<= 1) mx = fmaxf(mx, __shfl_xor(mx, off));
    if ((t & 63) == 0) wred[t >> 6] = mx;
    __syncthreads();
    mx = fmaxf(fmaxf(wred[0], wred[1]), fmaxf(wred[2], wred[3]));
    mx = fmaxf(mx, 1e-20f);
    const float inv = 127.0f / mx;
    if (t == 0) sw[b] = mx / 127.0f;
    uint2 o0 = {pack4(v, inv),     pack4(v + 4, inv)};
    uint2 o1 = {pack4(v + 8, inv), pack4(v + 12, inv)};
    *(uint2*)(Wq + (size_t)b * K_ + t * 8)        = o0;
    *(uint2*)(Wq + (size_t)b * K_ + 2048 + t * 8) = o1;
  } else {
    // ---- X row r: 4096 elems; thread handles 16 ----
    const int r = b - N_;
    const f32x4* px = (const f32x4*)(x + (size_t)r * K_ + t * 16);
    f32x4 a0 = px[0], a1 = px[1], a2 = px[2], a3 = px[3];
    float v[16];
#pragma unroll
    for (int j = 0; j < 4; ++j) { v[j] = a0[j]; v[4 + j] = a1[j]; v[8 + j] = a2[j]; v[12 + j] = a3[j]; }
    float mx = 0.f;
#pragma unroll
    for (int j = 0; j < 16; ++j) mx = fmaxf(mx, fabsf(v[j]));
#pragma unroll
    for (int off = 1; off < 64; off <<= 1) mx = fmaxf(mx, __shfl_xor(mx, off));
    if ((t & 63) == 0) wred[t >> 6] = mx;
    __syncthreads();
    mx = fmaxf(fmaxf(wred[0], wred[1]), fmaxf(wred[2], wred[3]));
    mx = fmaxf(mx, 1e-20f);
    const float inv = 127.0f / mx;
    if (t == 0) sx[r] = mx / 127.0f;
    uint4 o = {pack4(v, inv), pack4(v + 4, inv), pack4(v + 8, inv), pack4(v + 12, inv)};
    *(uint4*)(Xq + (size_t)r * K_ + t * 16) = o;
  }
}

// ---------------------------------------------------------------------------
// Kernel 2: 256x256x64 i8 GEMM, STAGGERED single-block tile, 2 barriers/tile.
// LDS 64 KiB: [2 bufs][A|B][256 x 64 i8]; chunk swizzle c' = c ^ ((row>>1)&3)
// (R11, conflict-free both sides).
// Per tile T (buf b = T&1), per wave:
//   issue 12 x ds_read_b128: B(4), A-half1(4), A-half2(4)
//       [halves: wm=0 waves quad0 then quad1; wm=1 waves quad1 then quad0 --
//        each SIMD hosts waves w and w+4 (wm 0 and 1), so siblings alternate
//        read-phase vs MFMA-phase: LDS serve overlaps MFMA per SIMD]
//   lgkm(4)  -> B + A-half1 served ; 16 MFMA (half1)
//   lgkm(0)  -> A-half2 served     ; 16 MFMA (half2)
//   BAR#1    -> every wave's buf-b reads served  => stage overwrite safe
//   stage T+2 -> buf b (4 GLDS: A x2, B x2)
//   vmcnt(4) -> T+1's 4 lines drained (T+2's 4 stay in flight)
//   BAR#2    -> buf[T+1] visible to all waves
// Prologue: [T0:4][T1:4], vmcnt(4), BAR.  T=NT-2: no stage, vmcnt(0).
// T=NT-1: no stage/vmcnt/barriers.
// ---------------------------------------------------------------------------
#define BM 256
#define BN 256
#define BK 64
#define NT (K_ / BK)          // 64 K-tiles

#define GLDS(g, l) __builtin_amdgcn_global_load_lds( \
    (const __attribute__((address_space(1))) void*)(g), \
    (__attribute__((address_space(3))) void*)(l), 16, 0, 0)

#define LGKM_WAIT(n) do { \
    asm volatile("s_waitcnt lgkmcnt(" #n ")" ::: "memory"); \
    __builtin_amdgcn_sched_barrier(0); \
  } while (0)

#define VM_WAIT(n) asm volatile("s_waitcnt vmcnt(" #n ")" ::: "memory")
#define MEMFENCE asm volatile("" ::: "memory")

// MODE: 0 steady, 1 = T==NT-2, 2 = T==NT-1
template<int MODE>
__device__ __forceinline__ void tile_step(
    int T, signed char (*lds)[2][16384], i32x4 (&acc)[8][4],
    const signed char* __restrict__ Ag,
    const signed char* __restrict__ Bg,
    int wm, int wn, int lrow, int cs16,
    int tid, int sr, int scs)
{
  const int b = T & 1;
  const int h1 = wm ? 64 : 0;          // staggered first half (row offset)
  const int h2 = 64 - h1;
  const int ab1 = h1 >> 4, ab2 = h2 >> 4;   // acc base (0 or 4)
  i32x4 av1[4], av2[4], bv[4];

  // ---- issue all 12 reads: B(4) first, then A-half1(4), A-half2(4) ----
#pragma unroll
  for (int n = 0; n < 4; ++n)
    bv[n] = *(const i32x4*)(const void*)(
        &lds[b][1][(wn * 64 + n * 16 + lrow) * 64 + cs16]);
  __builtin_amdgcn_sched_barrier(0);
#pragma unroll
  for (int m = 0; m < 4; ++m)
    av1[m] = *(const i32x4*)(const void*)(
        &lds[b][0][(wm * 128 + h1 + m * 16 + lrow) * 64 + cs16]);
  __builtin_amdgcn_sched_barrier(0);
#pragma unroll
  for (int m = 0; m < 4; ++m)
    av2[m] = *(const i32x4*)(const void*)(
        &lds[b][0][(wm * 128 + h2 + m * 16 + lrow) * 64 + cs16]);

  // ---- half 1 ----
  LGKM_WAIT(4);                        // B + A-half1 served
  __builtin_amdgcn_s_setprio(1);
#pragma unroll
  for (int n = 0; n < 4; ++n)
#pragma unroll
    for (int m = 0; m < 4; ++m)
      acc[ab1 + m][n] = __builtin_amdgcn_mfma_i32_16x16x64_i8(av1[m], bv[n], acc[ab1 + m][n], 0, 0, 0);
  __builtin_amdgcn_s_setprio(0);

  // ---- half 2 ----
  LGKM_WAIT(0);                        // A-half2 served
  __builtin_amdgcn_s_setprio(1);
#pragma unroll
  for (int n = 0; n < 4; ++n)
#pragma unroll
    for (int m = 0; m < 4; ++m)
      acc[ab2 + m][n] = __builtin_amdgcn_mfma_i32_16x16x64_i8(av2[m], bv[n], acc[ab2 + m][n], 0, 0, 0);
  __builtin_amdgcn_s_setprio(0);

  if (MODE == 2) return;               // last tile: epilogue follows

  // ---- BAR#1: all waves' buf-b reads served -> overwrite safe ----
  __builtin_amdgcn_s_barrier();
  MEMFENCE;
  if (MODE == 0) {
    GLDS(Ag + (size_t)(sr) * K_ + (T + 2) * BK + scs,       &lds[b][0][tid * 16]);
    GLDS(Ag + (size_t)(128 + sr) * K_ + (T + 2) * BK + scs, &lds[b][0][8192 + tid * 16]);
    GLDS(Bg + (size_t)(sr) * K_ + (T + 2) * BK + scs,       &lds[b][1][tid * 16]);
    GLDS(Bg + (size_t)(128 + sr) * K_ + (T + 2) * BK + scs, &lds[b][1][8192 + tid * 16]);
    VM_WAIT(4);                        // T+1's 4 drained; T+2's 4 in flight
  } else {
    VM_WAIT(0);                        // T = NT-2: drain T+1 completely
  }
  __builtin_amdgcn_s_barrier();        // BAR#2: buf[T+1] visible
  MEMFENCE;
}

__global__ __launch_bounds__(512, 2) void gemmq_kernel(
    const signed char* __restrict__ A,   // Xq [M_][K_] i8
    const signed char* __restrict__ B,   // Wq [N_][K_] i8
    const float* __restrict__ sx, const float* __restrict__ sw,
    float* __restrict__ C)
{
  __shared__ signed char lds[2][2][16384];  // 64 KiB

  // XCD-aware bijective swizzle (nwg = 512, 512 % 8 == 0)
  const int nwg = (M_ / BM) * (N_ / BN);
  const int bid = blockIdx.x;
  const int wg  = (bid % 8) * (nwg / 8) + bid / 8;
  const int tn  = wg % (N_ / BN);
  const int tm  = wg / (N_ / BN);
  const int brow = tm * BM, bcol = tn * BN;

  const int tid  = threadIdx.x;
  const int lane = tid & 63, w = tid >> 6;
  const int wm   = w >> 2, wn = w & 3;      // 2 (M) x 4 (N)
  const int lrow = lane & 15, hi2 = lane >> 4;
  const int cs16 = (hi2 ^ ((lrow >> 1) & 3)) * 16;       // swizzled read chunk
  const int sr  = tid >> 2;
  const int scs = ((tid & 3) ^ ((tid >> 3) & 3)) * 16;   // inv-swizzled source

  const signed char* Ag = A + (size_t)brow * K_;
  const signed char* Bg = B + (size_t)bcol * K_;

  i32x4 acc[8][4];
#pragma unroll
  for (int m = 0; m < 8; ++m)
#pragma unroll
    for (int n = 0; n < 4; ++n)
      acc[m][n] = i32x4{0, 0, 0, 0};

  // ---- prologue: [tile0: A,A,B,B][tile1: A,A,B,B]; vmcnt(4) drains tile 0 ----
  GLDS(Ag + (size_t)(sr) * K_ + scs,            &lds[0][0][tid * 16]);
  GLDS(Ag + (size_t)(128 + sr) * K_ + scs,      &lds[0][0][8192 + tid * 16]);
  GLDS(Bg + (size_t)(sr) * K_ + scs,            &lds[0][1][tid * 16]);
  GLDS(Bg + (size_t)(128 + sr) * K_ + scs,      &lds[0][1][8192 + tid * 16]);
  GLDS(Ag + (size_t)(sr) * K_ + BK + scs,       &lds[1][0][tid * 16]);
  GLDS(Ag + (size_t)(128 + sr) * K_ + BK + scs, &lds[1][0][8192 + tid * 16]);
  GLDS(Bg + (size_t)(sr) * K_ + BK + scs,       &lds[1][1][tid * 16]);
  GLDS(Bg + (size_t)(128 + sr) * K_ + BK + scs, &lds[1][1][8192 + tid * 16]);
  VM_WAIT(4);
  __builtin_amdgcn_s_barrier();
  MEMFENCE;

  for (int T = 0; T < NT - 2; ++T)
    tile_step<0>(T, lds, acc, Ag, Bg, wm, wn, lrow, cs16, tid, sr, scs);
  tile_step<1>(NT - 2, lds, acc, Ag, Bg, wm, wn, lrow, cs16, tid, sr, scs);
  tile_step<2>(NT - 1, lds, acc, Ag, Bg, wm, wn, lrow, cs16, tid, sr, scs);

  // epilogue: C/D layout col = lane&15, row = (lane>>4)*4 + reg  (shape-
  // determined, dtype-independent).  out = acc * sx[row] * sw[col].
  const int crow = brow + wm * 128 + hi2 * 4;
  const int ccol = bcol + wn * 64 + lrow;
  float swv[4];
#pragma unroll
  for (int n = 0; n < 4; ++n) swv[n] = sw[ccol + n * 16];
#pragma unroll
  for (int m = 0; m < 8; ++m)
#pragma unroll
    for (int r = 0; r < 4; ++r) {
      const int row = crow + m * 16 + r;
      const float sxv = sx[row];
#pragma unroll
      for (int n = 0; n < 4; ++n)
        C[(size_t)row * N_ + ccol + n * 16] = (float)acc[m][n][r] * sxv * swv[n];
    }
}

// ---------------------------------------------------------------------------
// Fallback (ws too small): fp32 tiled GEMM with on-the-fly dequant
// ---------------------------------------------------------------------------
__global__ __launch_bounds__(256) void fallback_kernel(
    const float* __restrict__ x, const float* __restrict__ cb,
    const float* __restrict__ scales, const int* __restrict__ idx,
    const int* __restrict__ signs, float* __restrict__ out)
{
  __shared__ float Xs[32][33];
  __shared__ float Ws[32][33];
  const int t = threadIdx.x;
  const int tx = t & 31, ty = t >> 5;
  const int brow = blockIdx.y * 32, bcol = blockIdx.x * 32;
  float acc[4] = {0.f, 0.f, 0.f, 0.f};

  for (int k0 = 0; k0 < K_; k0 += 32) {
    for (int l = t; l < 1024; l += 256) {
      const int r = l >> 5, c = l & 31;
      Xs[r][c] = x[(size_t)(brow + r) * K_ + k0 + c];
      const int n = bcol + r;
      const size_t flat = (size_t)n * K_ + (k0 + c);
      const int g = (int)(flat >> 3), j = (int)(flat & 7);
      float wv = cb[idx[g] * 8 + j] * scales[n];
      if (!((signs[g] >> (7 - j)) & 1)) wv = -wv;
      Ws[r][c] = wv;
    }
    __syncthreads();
#pragma unroll
    for (int kk = 0; kk < 32; ++kk) {
      const float wv = Ws[tx][kk];
      acc[0] += Xs[ty][kk] * wv;
      acc[1] += Xs[ty + 8][kk] * wv;
      acc[2] += Xs[ty + 16][kk] * wv;
      acc[3] += Xs[ty + 24][kk] * wv;
    }
    __syncthreads();
  }
#pragma unroll
  for (int q = 0; q < 4; ++q)
    out[(size_t)(brow + ty + 8 * q) * N_ + bcol + tx] = acc[q];
}

// ---------------------------------------------------------------------------
extern "C" void kernel_launch(void* const* d_in, const int* in_sizes, int n_in,
                              void* d_out, int out_size, void* d_ws, size_t ws_size,
                              hipStream_t stream)
{
  const float* x      = (const float*)d_in[0];
  const float* cb     = (const float*)d_in[1];
  const float* scales = (const float*)d_in[2];
  const int*   idx    = (const int*)d_in[3];
  const int*   signs  = (const int*)d_in[4];
  float* out = (float*)d_out;

  const size_t wq = (size_t)N_ * K_;        // 16.8 MB i8
  const size_t xq = (size_t)M_ * K_;        // 33.6 MB i8
  const size_t need = wq + xq + (N_ + M_) * sizeof(float);

  if (ws_size >= need) {
    signed char* Wq = (signed char*)d_ws;
    signed char* Xq = Wq + wq;
    float* swp = (float*)(Xq + xq);
    float* sxp = swp + N_;
    prep_kernel<<<N_ + M_, 256, 0, stream>>>(x, cb, scales, idx, signs, Wq, Xq, swp, sxp);
    gemmq_kernel<<<(M_ / BM) * (N_ / BN), 512, 0, stream>>>(Xq, Wq, sxp, swp, out);
  } else {
    fallback_kernel<<<dim3(N_ / 32, M_ / 32), 256, 0, stream>>>(x, cb, scales, idx, signs, out);
  }
}

// Round 13
// 200.838 us; speedup vs baseline: 13.4374x; 13.4374x over previous
//
#include <hip/hip_runtime.h>

// SymHQLinear: out[8192,4096] = x @ W^T; W[4096,4096] dequantized from
// codebook[4096,8] + per-row scales + packed sign bits.
// Strategy: per-row symmetric i8 quantization of X and W, mfma_i32_16x16x64_i8
// GEMM, fp32 epilogue scales.  R13 = R12's wave-group stagger with the
// rule-#20 fix: acc indices are TEMPLATE constants (halves<H1>), selected by
// a wave-uniform branch -- no runtime-indexed ext_vector arrays.
#define M_ 8192   // TOKENS
#define N_ 4096   // OUT
#define K_ 4096   // IN

typedef float f32x4 __attribute__((ext_vector_type(4)));
typedef int   i32x4 __attribute__((ext_vector_type(4)));

// ---------------------------------------------------------------------------
// Kernel 1 (fused prep): blocks [0, 4096): W row -> dequant, row-max, i8 + sw
//                        blocks [4096, 12288): X row -> row-max, i8 + sx
// ---------------------------------------------------------------------------
__device__ __forceinline__ unsigned pack4(const float* v, float inv) {
  unsigned r = 0;
#pragma unroll
  for (int j = 0; j < 4; ++j) {
    int q = (int)rintf(v[j] * inv);
    q = q < -127 ? -127 : (q > 127 ? 127 : q);
    r |= ((unsigned)(q & 0xff)) << (8 * j);
  }
  return r;
}

__global__ __launch_bounds__(256) void prep_kernel(
    const float* __restrict__ x, const float* __restrict__ cb,
    const float* __restrict__ scales, const int* __restrict__ idx,
    const int* __restrict__ signs,
    signed char* __restrict__ Wq, signed char* __restrict__ Xq,
    float* __restrict__ sw, float* __restrict__ sx)
{
  __shared__ float wred[4];
  const int b = blockIdx.x, t = threadIdx.x;

  if (b < N_) {
    const float s = scales[b];
    const int g0 = b * 512 + t, g1 = g0 + 256;
    const int c0 = idx[g0], c1 = idx[g1];
    const int sb0 = signs[g0], sb1 = signs[g1];
    const float* cv0 = cb + c0 * 8;
    const float* cv1 = cb + c1 * 8;
    float v[16];
    float mx = 0.f;
#pragma unroll
    for (int j = 0; j < 8; ++j) {
      float a = cv0[j] * s;
      if (!((sb0 >> (7 - j)) & 1)) a = -a;
      v[j] = a; mx = fmaxf(mx, fabsf(a));
    }
#pragma unroll
    for (int j = 0; j < 8; ++j) {
      float a = cv1[j] * s;
      if (!((sb1 >> (7 - j)) & 1)) a = -a;
      v[8 + j] = a; mx = fmaxf(mx, fabsf(a));
    }
#pragma unroll
    for (int off = 1; off < 64; off <<= 1) mx = fmaxf(mx, __shfl_xor(mx, off));
    if ((t & 63) == 0) wred[t >> 6] = mx;
    __syncthreads();
    mx = fmaxf(fmaxf(wred[0], wred[1]), fmaxf(wred[2], wred[3]));
    mx = fmaxf(mx, 1e-20f);
    const float inv = 127.0f / mx;
    if (t == 0) sw[b] = mx / 127.0f;
    uint2 o0 = {pack4(v, inv),     pack4(v + 4, inv)};
    uint2 o1 = {pack4(v + 8, inv), pack4(v + 12, inv)};
    *(uint2*)(Wq + (size_t)b * K_ + t * 8)        = o0;
    *(uint2*)(Wq + (size_t)b * K_ + 2048 + t * 8) = o1;
  } else {
    const int r = b - N_;
    const f32x4* px = (const f32x4*)(x + (size_t)r * K_ + t * 16);
    f32x4 a0 = px[0], a1 = px[1], a2 = px[2], a3 = px[3];
    float v[16];
#pragma unroll
    for (int j = 0; j < 4; ++j) { v[j] = a0[j]; v[4 + j] = a1[j]; v[8 + j] = a2[j]; v[12 + j] = a3[j]; }
    float mx = 0.f;
#pragma unroll
    for (int j = 0; j < 16; ++j) mx = fmaxf(mx, fabsf(v[j]));
#pragma unroll
    for (int off = 1; off < 64; off <<= 1) mx = fmaxf(mx, __shfl_xor(mx, off));
    if ((t & 63) == 0) wred[t >> 6] = mx;
    __syncthreads();
    mx = fmaxf(fmaxf(wred[0], wred[1]), fmaxf(wred[2], wred[3]));
    mx = fmaxf(mx, 1e-20f);
    const float inv = 127.0f / mx;
    if (t == 0) sx[r] = mx / 127.0f;
    uint4 o = {pack4(v, inv), pack4(v + 4, inv), pack4(v + 8, inv), pack4(v + 12, inv)};
    *(uint4*)(Xq + (size_t)r * K_ + t * 16) = o;
  }
}

// ---------------------------------------------------------------------------
// Kernel 2: 256x256x64 i8 GEMM, staggered single-block tile, 2 barriers/tile.
// LDS 64 KiB: [2 bufs][A|B][256 x 64 i8]; chunk swizzle c' = c ^ ((row>>1)&3).
// Stagger: waves with wm=0 compute A-quad0 then quad1; wm=1 the reverse.
// SIMD s hosts waves s and s+4 (wm=0 and wm=1) -> siblings alternate
// LDS-read phase vs MFMA phase; LDS serve overlaps MFMA per SIMD.
// Rule-#20 safe: halves<H1> templates make every acc index compile-time.
// ---------------------------------------------------------------------------
#define BM 256
#define BN 256
#define BK 64
#define NT (K_ / BK)          // 64 K-tiles

#define GLDS(g, l) __builtin_amdgcn_global_load_lds( \
    (const __attribute__((address_space(1))) void*)(g), \
    (__attribute__((address_space(3))) void*)(l), 16, 0, 0)

#define LGKM_WAIT(n) do { \
    asm volatile("s_waitcnt lgkmcnt(" #n ")" ::: "memory"); \
    __builtin_amdgcn_sched_barrier(0); \
  } while (0)

#define VM_WAIT(n) asm volatile("s_waitcnt vmcnt(" #n ")" ::: "memory")
#define MEMFENCE asm volatile("" ::: "memory")

// Read 12 b128 + two 16-MFMA halves.  H1 in {0,64} is COMPILE-TIME: acc
// indices AB1/AB2 are constants -> registers stay registers (rule #20).
template<int H1>
__device__ __forceinline__ void halves(
    const signed char* __restrict__ A_lds,   // lds[b][0]
    const signed char* __restrict__ B_lds,   // lds[b][1]
    i32x4 (&acc)[8][4], int wm128, int wn, int lrow, int cs16)
{
  constexpr int H2  = 64 - H1;
  constexpr int AB1 = H1 >> 4;              // 0 or 4
  constexpr int AB2 = H2 >> 4;
  i32x4 av1[4], av2[4], bv[4];

#pragma unroll
  for (int n = 0; n < 4; ++n)
    bv[n] = *(const i32x4*)(const void*)(
        &B_lds[(wn * 64 + n * 16 + lrow) * 64 + cs16]);
  __builtin_amdgcn_sched_barrier(0);
#pragma unroll
  for (int m = 0; m < 4; ++m)
    av1[m] = *(const i32x4*)(const void*)(
        &A_lds[(wm128 + H1 + m * 16 + lrow) * 64 + cs16]);
  __builtin_amdgcn_sched_barrier(0);
#pragma unroll
  for (int m = 0; m < 4; ++m)
    av2[m] = *(const i32x4*)(const void*)(
        &A_lds[(wm128 + H2 + m * 16 + lrow) * 64 + cs16]);

  LGKM_WAIT(4);                        // B + A-half1 served
  __builtin_amdgcn_s_setprio(1);
#pragma unroll
  for (int n = 0; n < 4; ++n)
#pragma unroll
    for (int m = 0; m < 4; ++m)
      acc[AB1 + m][n] = __builtin_amdgcn_mfma_i32_16x16x64_i8(av1[m], bv[n], acc[AB1 + m][n], 0, 0, 0);
  __builtin_amdgcn_s_setprio(0);

  LGKM_WAIT(0);                        // A-half2 served
  __builtin_amdgcn_s_setprio(1);
#pragma unroll
  for (int n = 0; n < 4; ++n)
#pragma unroll
    for (int m = 0; m < 4; ++m)
      acc[AB2 + m][n] = __builtin_amdgcn_mfma_i32_16x16x64_i8(av2[m], bv[n], acc[AB2 + m][n], 0, 0, 0);
  __builtin_amdgcn_s_setprio(0);
}

// MODE: 0 steady, 1 = T==NT-2, 2 = T==NT-1
template<int MODE>
__device__ __forceinline__ void tile_step(
    int T, signed char (*lds)[2][16384], i32x4 (&acc)[8][4],
    const signed char* __restrict__ Ag,
    const signed char* __restrict__ Bg,
    int wm, int wn, int lrow, int cs16,
    int tid, int sr, int scs)
{
  const int b = T & 1;
  const int wm128 = wm * 128;

  // wave-uniform branch; no barriers inside -> convergence safe
  if (wm)
    halves<64>(&lds[b][0][0], &lds[b][1][0], acc, wm128, wn, lrow, cs16);
  else
    halves<0>(&lds[b][0][0], &lds[b][1][0], acc, wm128, wn, lrow, cs16);

  if (MODE == 2) return;               // last tile: epilogue follows

  // ---- BAR#1: all waves' buf-b reads served -> overwrite safe ----
  __builtin_amdgcn_s_barrier();
  MEMFENCE;
  if (MODE == 0) {
    GLDS(Ag + (size_t)(sr) * K_ + (T + 2) * BK + scs,       &lds[b][0][tid * 16]);
    GLDS(Ag + (size_t)(128 + sr) * K_ + (T + 2) * BK + scs, &lds[b][0][8192 + tid * 16]);
    GLDS(Bg + (size_t)(sr) * K_ + (T + 2) * BK + scs,       &lds[b][1][tid * 16]);
    GLDS(Bg + (size_t)(128 + sr) * K_ + (T + 2) * BK + scs, &lds[b][1][8192 + tid * 16]);
    VM_WAIT(4);                        // T+1's 4 drained; T+2's 4 in flight
  } else {
    VM_WAIT(0);                        // T = NT-2: drain fully
  }
  __builtin_amdgcn_s_barrier();        // BAR#2: buf[T+1] visible
  MEMFENCE;
}

__global__ __launch_bounds__(512, 2) void gemmq_kernel(
    const signed char* __restrict__ A,   // Xq [M_][K_] i8
    const signed char* __restrict__ B,   // Wq [N_][K_] i8
    const float* __restrict__ sx, const float* __restrict__ sw,
    float* __restrict__ C)
{
  __shared__ signed char lds[2][2][16384];  // 64 KiB

  // XCD-aware bijective swizzle (nwg = 512, 512 % 8 == 0)
  const int nwg = (M_ / BM) * (N_ / BN);
  const int bid = blockIdx.x;
  const int wg  = (bid % 8) * (nwg / 8) + bid / 8;
  const int tn  = wg % (N_ / BN);
  const int tm  = wg / (N_ / BN);
  const int brow = tm * BM, bcol = tn * BN;

  const int tid  = threadIdx.x;
  const int lane = tid & 63, w = tid >> 6;
  const int wm   = w >> 2, wn = w & 3;      // 2 (M) x 4 (N)
  const int lrow = lane & 15, hi2 = lane >> 4;
  const int cs16 = (hi2 ^ ((lrow >> 1) & 3)) * 16;       // swizzled read chunk
  const int sr  = tid >> 2;
  const int scs = ((tid & 3) ^ ((tid >> 3) & 3)) * 16;   // inv-swizzled source

  const signed char* Ag = A + (size_t)brow * K_;
  const signed char* Bg = B + (size_t)bcol * K_;

  i32x4 acc[8][4];
#pragma unroll
  for (int m = 0; m < 8; ++m)
#pragma unroll
    for (int n = 0; n < 4; ++n)
      acc[m][n] = i32x4{0, 0, 0, 0};

  // ---- prologue: [tile0: A,A,B,B][tile1: A,A,B,B]; vmcnt(4) drains tile 0 --
  GLDS(Ag + (size_t)(sr) * K_ + scs,            &lds[0][0][tid * 16]);
  GLDS(Ag + (size_t)(128 + sr) * K_ + scs,      &lds[0][0][8192 + tid * 16]);
  GLDS(Bg + (size_t)(sr) * K_ + scs,            &lds[0][1][tid * 16]);
  GLDS(Bg + (size_t)(128 + sr) * K_ + scs,      &lds[0][1][8192 + tid * 16]);
  GLDS(Ag + (size_t)(sr) * K_ + BK + scs,       &lds[1][0][tid * 16]);
  GLDS(Ag + (size_t)(128 + sr) * K_ + BK + scs, &lds[1][0][8192 + tid * 16]);
  GLDS(Bg + (size_t)(sr) * K_ + BK + scs,       &lds[1][1][tid * 16]);
  GLDS(Bg + (size_t)(128 + sr) * K_ + BK + scs, &lds[1][1][8192 + tid * 16]);
  VM_WAIT(4);
  __builtin_amdgcn_s_barrier();
  MEMFENCE;

  for (int T = 0; T < NT - 2; ++T)
    tile_step<0>(T, lds, acc, Ag, Bg, wm, wn, lrow, cs16, tid, sr, scs);
  tile_step<1>(NT - 2, lds, acc, Ag, Bg, wm, wn, lrow, cs16, tid, sr, scs);
  tile_step<2>(NT - 1, lds, acc, Ag, Bg, wm, wn, lrow, cs16, tid, sr, scs);

  // epilogue: C/D layout col = lane&15, row = (lane>>4)*4 + reg.
  // out = acc * sx[row] * sw[col].
  const int crow = brow + wm * 128 + hi2 * 4;
  const int ccol = bcol + wn * 64 + lrow;
  float swv[4];
#pragma unroll
  for (int n = 0; n < 4; ++n) swv[n] = sw[ccol + n * 16];
#pragma unroll
  for (int m = 0; m < 8; ++m)
#pragma unroll
    for (int r = 0; r < 4; ++r) {
      const int row = crow + m * 16 + r;
      const float sxv = sx[row];
#pragma unroll
      for (int n = 0; n < 4; ++n)
        C[(size_t)row * N_ + ccol + n * 16] = (float)acc[m][n][r] * sxv * swv[n];
    }
}

// ---------------------------------------------------------------------------
// Fallback (ws too small): fp32 tiled GEMM with on-the-fly dequant
// ---------------------------------------------------------------------------
__global__ __launch_bounds__(256) void fallback_kernel(
    const float* __restrict__ x, const float* __restrict__ cb,
    const float* __restrict__ scales, const int* __restrict__ idx,
    const int* __restrict__ signs, float* __restrict__ out)
{
  __shared__ float Xs[32][33];
  __shared__ float Ws[32][33];
  const int t = threadIdx.x;
  const int tx = t & 31, ty = t >> 5;
  const int brow = blockIdx.y * 32, bcol = blockIdx.x * 32;
  float acc[4] = {0.f, 0.f, 0.f, 0.f};

  for (int k0 = 0; k0 < K_; k0 += 32) {
    for (int l = t; l < 1024; l += 256) {
      const int r = l >> 5, c = l & 31;
      Xs[r][c] = x[(size_t)(brow + r) * K_ + k0 + c];
      const int n = bcol + r;
      const size_t flat = (size_t)n * K_ + (k0 + c);
      const int g = (int)(flat >> 3), j = (int)(flat & 7);
      float wv = cb[idx[g] * 8 + j] * scales[n];
      if (!((signs[g] >> (7 - j)) & 1)) wv = -wv;
      Ws[r][c] = wv;
    }
    __syncthreads();
#pragma unroll
    for (int kk = 0; kk < 32; ++kk) {
      const float wv = Ws[tx][kk];
      acc[0] += Xs[ty][kk] * wv;
      acc[1] += Xs[ty + 8][kk] * wv;
      acc[2] += Xs[ty + 16][kk] * wv;
      acc[3] += Xs[ty + 24][kk] * wv;
    }
    __syncthreads();
  }
#pragma unroll
  for (int q = 0; q < 4; ++q)
    out[(size_t)(brow + ty + 8 * q) * N_ + bcol + tx] = acc[q];
}

// ---------------------------------------------------------------------------
extern "C" void kernel_launch(void* const* d_in, const int* in_sizes, int n_in,
                              void* d_out, int out_size, void* d_ws, size_t ws_size,
                              hipStream_t stream)
{
  const float* x      = (const float*)d_in[0];
  const float* cb     = (const float*)d_in[1];
  const float* scales = (const float*)d_in[2];
  const int*   idx    = (const int*)d_in[3];
  const int*   signs  = (const int*)d_in[4];
  float* out = (float*)d_out;

  const size_t wq = (size_t)N_ * K_;        // 16.8 MB i8
  const size_t xq = (size_t)M_ * K_;        // 33.6 MB i8
  const size_t need = wq + xq + (N_ + M_) * sizeof(float);

  if (ws_size >= need) {
    signed char* Wq = (signed char*)d_ws;
    signed char* Xq = Wq + wq;
    float* swp = (float*)(Xq + xq);
    float* sxp = swp + N_;
    prep_kernel<<<N_ + M_, 256, 0, stream>>>(x, cb, scales, idx, signs, Wq, Xq, swp, sxp);
    gemmq_kernel<<<(M_ / BM) * (N_ / BN), 512, 0, stream>>>(Xq, Wq, sxp, swp, out);
  } else {
    fallback_kernel<<<dim3(N_ / 32, M_ / 32), 256, 0, stream>>>(x, cb, scales, idx, signs, out);
  }
}

// Round 14
// 186.594 us; speedup vs baseline: 14.4632x; 1.0763x over previous
//
#include <hip/hip_runtime.h>

// SymHQLinear: out[8192,4096] = x @ W^T; W[4096,4096] dequantized from
// codebook[4096,8] + per-row scales + packed sign bits.
// Strategy (R11, the measured optimum of this session): per-row symmetric i8
// quantization of X and W, mfma_i32_16x16x64_i8 GEMM, fp32 epilogue scales.
// LDS chunk swizzle c^=(row>>1)&3 -> 0 bank conflicts.  2-phase tile with
// distributed staging (A in P0, B in P1) + counted vmcnt(2).
#define M_ 8192   // TOKENS
#define N_ 4096   // OUT
#define K_ 4096   // IN

typedef float f32x4 __attribute__((ext_vector_type(4)));
typedef int   i32x4 __attribute__((ext_vector_type(4)));

// ---------------------------------------------------------------------------
// Kernel 1 (fused prep): blocks [0, 4096): W row -> dequant, row-max, i8 + sw
//                        blocks [4096, 12288): X row -> row-max, i8 + sx
// ---------------------------------------------------------------------------
__device__ __forceinline__ unsigned pack4(const float* v, float inv) {
  unsigned r = 0;
#pragma unroll
  for (int j = 0; j < 4; ++j) {
    int q = (int)rintf(v[j] * inv);
    q = q < -127 ? -127 : (q > 127 ? 127 : q);
    r |= ((unsigned)(q & 0xff)) << (8 * j);
  }
  return r;
}

__global__ __launch_bounds__(256) void prep_kernel(
    const float* __restrict__ x, const float* __restrict__ cb,
    const float* __restrict__ scales, const int* __restrict__ idx,
    const int* __restrict__ signs,
    signed char* __restrict__ Wq, signed char* __restrict__ Xq,
    float* __restrict__ sw, float* __restrict__ sx)
{
  __shared__ float wred[4];
  const int b = blockIdx.x, t = threadIdx.x;

  if (b < N_) {
    // ---- W row b: 512 groups; thread handles groups t and t+256 ----
    const float s = scales[b];
    const int g0 = b * 512 + t, g1 = g0 + 256;
    const int c0 = idx[g0], c1 = idx[g1];
    const int sb0 = signs[g0], sb1 = signs[g1];
    const float* cv0 = cb + c0 * 8;
    const float* cv1 = cb + c1 * 8;
    float v[16];
    float mx = 0.f;
#pragma unroll
    for (int j = 0; j < 8; ++j) {
      float a = cv0[j] * s;
      if (!((sb0 >> (7 - j)) & 1)) a = -a;
      v[j] = a; mx = fmaxf(mx, fabsf(a));
    }
#pragma unroll
    for (int j = 0; j < 8; ++j) {
      float a = cv1[j] * s;
      if (!((sb1 >> (7 - j)) & 1)) a = -a;
      v[8 + j] = a; mx = fmaxf(mx, fabsf(a));
    }
#pragma unroll
    for (int off = 1; off < 64; off <<= 1) mx = fmaxf(mx, __shfl_xor(mx, off));
    if ((t & 63) == 0) wred[t >> 6] = mx;
    __syncthreads();
    mx = fmaxf(fmaxf(wred[0], wred[1]), fmaxf(wred[2], wred[3]));
    mx = fmaxf(mx, 1e-20f);
    const float inv = 127.0f / mx;
    if (t == 0) sw[b] = mx / 127.0f;
    uint2 o0 = {pack4(v, inv),     pack4(v + 4, inv)};
    uint2 o1 = {pack4(v + 8, inv), pack4(v + 12, inv)};
    *(uint2*)(Wq + (size_t)b * K_ + t * 8)        = o0;
    *(uint2*)(Wq + (size_t)b * K_ + 2048 + t * 8) = o1;
  } else {
    // ---- X row r: 4096 elems; thread handles 16 ----
    const int r = b - N_;
    const f32x4* px = (const f32x4*)(x + (size_t)r * K_ + t * 16);
    f32x4 a0 = px[0], a1 = px[1], a2 = px[2], a3 = px[3];
    float v[16];
#pragma unroll
    for (int j = 0; j < 4; ++j) { v[j] = a0[j]; v[4 + j] = a1[j]; v[8 + j] = a2[j]; v[12 + j] = a3[j]; }
    float mx = 0.f;
#pragma unroll
    for (int j = 0; j < 16; ++j) mx = fmaxf(mx, fabsf(v[j]));
#pragma unroll
    for (int off = 1; off < 64; off <<= 1) mx = fmaxf(mx, __shfl_xor(mx, off));
    if ((t & 63) == 0) wred[t >> 6] = mx;
    __syncthreads();
    mx = fmaxf(fmaxf(wred[0], wred[1]), fmaxf(wred[2], wred[3]));
    mx = fmaxf(mx, 1e-20f);
    const float inv = 127.0f / mx;
    if (t == 0) sx[r] = mx / 127.0f;
    uint4 o = {pack4(v, inv), pack4(v + 4, inv), pack4(v + 8, inv), pack4(v + 12, inv)};
    *(uint4*)(Xq + (size_t)r * K_ + t * 16) = o;
  }
}

// ---------------------------------------------------------------------------
// Kernel 2: 256x256x64 i8 GEMM, 2 phases/tile, mfma_i32_16x16x64_i8.
// LDS 64 KiB: [2 bufs][A|B][256 x 64 i8].
// SWIZZLE: 16B-chunk c' = c ^ ((row>>1)&3) -> quarter-wave reads spread rows
// over all 8 bank-quads, 2 lanes/quad = free (m136).  Both-sides (rule 21):
// linear GLDS dest + inverse-swizzled global SOURCE col + swizzled read chunk.
//   P0: read A-lo(4)+B(4); stage A(T+1)->nb ; BAR; lgkm0; 16 MFMA; BAR
//   P1: read A-hi(4);      stage B(T+2)->b  ; BAR; lgkm0; 16 MFMA; vmcnt(2); BAR
// vmcnt @ T P1-end: oldest [B(T+1):2][A(T+1):2][B(T+2):2] -> keep 2 drains
// all tile-(T+1) data.  Prologue: [A0:2][B0:2][B1:2], vmcnt(2) drains tile 0.
// ---------------------------------------------------------------------------
#define BM 256
#define BN 256
#define BK 64
#define NT (K_ / BK)          // 64 K-tiles

#define GLDS(g, l) __builtin_amdgcn_global_load_lds( \
    (const __attribute__((address_space(1))) void*)(g), \
    (__attribute__((address_space(3))) void*)(l), 16, 0, 0)

#define LGKM0 do { \
    asm volatile("s_waitcnt lgkmcnt(0)" ::: "memory"); \
    __builtin_amdgcn_sched_barrier(0); \
  } while (0)

#define VM_WAIT(n) asm volatile("s_waitcnt vmcnt(" #n ")" ::: "memory")
#define MEMFENCE asm volatile("" ::: "memory")

// MODE: 0 steady, 1 = T==NT-2, 2 = T==NT-1
template<int MODE>
__device__ __forceinline__ void tile_step(
    int T, signed char (*lds)[2][16384], i32x4 (&acc)[8][4],
    const signed char* __restrict__ Ag,
    const signed char* __restrict__ Bg,
    int wm, int wn, int lrow, int cs16,   // cs16 = (hi2 ^ ((lrow>>1)&3)) * 16
    int tid, int sr, int scs)             // scs = inv-swizzled staging col
{
  const int b = T & 1, nb = b ^ 1;
  i32x4 av[4], bv[4];

  // ================= P0: read A-lo(4)+B(4); stage A(T+1) =================
#pragma unroll
  for (int m = 0; m < 4; ++m)
    av[m] = *(const i32x4*)(const void*)(
        &lds[b][0][(wm * 128 + m * 16 + lrow) * 64 + cs16]);
#pragma unroll
  for (int n = 0; n < 4; ++n)
    bv[n] = *(const i32x4*)(const void*)(
        &lds[b][1][(wn * 64 + n * 16 + lrow) * 64 + cs16]);
  if (MODE <= 1) {
    GLDS(Ag + (size_t)(sr) * K_ + (T + 1) * BK + scs,       &lds[nb][0][tid * 16]);
    GLDS(Ag + (size_t)(128 + sr) * K_ + (T + 1) * BK + scs, &lds[nb][0][8192 + tid * 16]);
  }
  __builtin_amdgcn_s_barrier();
  LGKM0;
  __builtin_amdgcn_s_setprio(1);
#pragma unroll
  for (int n = 0; n < 4; ++n)
#pragma unroll
    for (int m = 0; m < 4; ++m)
      acc[m][n] = __builtin_amdgcn_mfma_i32_16x16x64_i8(av[m], bv[n], acc[m][n], 0, 0, 0);
  __builtin_amdgcn_s_setprio(0);
  __builtin_amdgcn_s_barrier();
  MEMFENCE;

  // ================= P1: read A-hi(4); stage B(T+2); vmcnt ================
#pragma unroll
  for (int m = 0; m < 4; ++m)
    av[m] = *(const i32x4*)(const void*)(
        &lds[b][0][(wm * 128 + 64 + m * 16 + lrow) * 64 + cs16]);
  if (MODE == 0) {
    GLDS(Bg + (size_t)(sr) * K_ + (T + 2) * BK + scs,       &lds[b][1][tid * 16]);
    GLDS(Bg + (size_t)(128 + sr) * K_ + (T + 2) * BK + scs, &lds[b][1][8192 + tid * 16]);
  }
  __builtin_amdgcn_s_barrier();
  LGKM0;
  __builtin_amdgcn_s_setprio(1);
#pragma unroll
  for (int n = 0; n < 4; ++n)
#pragma unroll
    for (int m = 0; m < 4; ++m)
      acc[4 + m][n] = __builtin_amdgcn_mfma_i32_16x16x64_i8(av[m], bv[n], acc[4 + m][n], 0, 0, 0);
  __builtin_amdgcn_s_setprio(0);
  if (MODE == 0)      VM_WAIT(2);     // drains all tile-(T+1) data (ledger)
  else if (MODE == 1) VM_WAIT(0);     // drains A(NT-1), B(NT-1)
  __builtin_amdgcn_s_barrier();
  MEMFENCE;
}

__global__ __launch_bounds__(512, 2) void gemmq_kernel(
    const signed char* __restrict__ A,   // Xq [M_][K_] i8
    const signed char* __restrict__ B,   // Wq [N_][K_] i8
    const float* __restrict__ sx, const float* __restrict__ sw,
    float* __restrict__ C)
{
  __shared__ signed char lds[2][2][16384];  // 64 KiB

  // XCD-aware bijective swizzle (nwg = 512, 512 % 8 == 0)
  const int nwg = (M_ / BM) * (N_ / BN);
  const int bid = blockIdx.x;
  const int wg  = (bid % 8) * (nwg / 8) + bid / 8;
  const int tn  = wg % (N_ / BN);
  const int tm  = wg / (N_ / BN);
  const int brow = tm * BM, bcol = tn * BN;

  const int tid  = threadIdx.x;
  const int lane = tid & 63, w = tid >> 6;
  const int wm   = w >> 2, wn = w & 3;      // 2 (M) x 4 (N)
  const int lrow = lane & 15, hi2 = lane >> 4;
  const int cs16 = (hi2 ^ ((lrow >> 1) & 3)) * 16;       // swizzled read chunk
  const int sr  = tid >> 2;
  const int scs = ((tid & 3) ^ ((tid >> 3) & 3)) * 16;   // inv-swizzled source

  const signed char* Ag = A + (size_t)brow * K_;
  const signed char* Bg = B + (size_t)bcol * K_;

  i32x4 acc[8][4];
#pragma unroll
  for (int m = 0; m < 8; ++m)
#pragma unroll
    for (int n = 0; n < 4; ++n)
      acc[m][n] = i32x4{0, 0, 0, 0};

  // ---- prologue: [A(0):2][B(0):2][B(1):2]; vmcnt(2) drains tile 0 ----
  GLDS(Ag + (size_t)(sr) * K_ + scs,            &lds[0][0][tid * 16]);
  GLDS(Ag + (size_t)(128 + sr) * K_ + scs,      &lds[0][0][8192 + tid * 16]);
  GLDS(Bg + (size_t)(sr) * K_ + scs,            &lds[0][1][tid * 16]);
  GLDS(Bg + (size_t)(128 + sr) * K_ + scs,      &lds[0][1][8192 + tid * 16]);
  GLDS(Bg + (size_t)(sr) * K_ + BK + scs,       &lds[1][1][tid * 16]);
  GLDS(Bg + (size_t)(128 + sr) * K_ + BK + scs, &lds[1][1][8192 + tid * 16]);
  VM_WAIT(2);
  __builtin_amdgcn_s_barrier();
  MEMFENCE;

  for (int T = 0; T < NT - 2; ++T)
    tile_step<0>(T, lds, acc, Ag, Bg, wm, wn, lrow, cs16, tid, sr, scs);
  tile_step<1>(NT - 2, lds, acc, Ag, Bg, wm, wn, lrow, cs16, tid, sr, scs);
  tile_step<2>(NT - 1, lds, acc, Ag, Bg, wm, wn, lrow, cs16, tid, sr, scs);

  // epilogue: C/D layout col = lane&15, row = (lane>>4)*4 + reg  (shape-
  // determined, dtype-independent).  out = acc * sx[row] * sw[col].
  const int crow = brow + wm * 128 + hi2 * 4;
  const int ccol = bcol + wn * 64 + lrow;
  float swv[4];
#pragma unroll
  for (int n = 0; n < 4; ++n) swv[n] = sw[ccol + n * 16];
#pragma unroll
  for (int m = 0; m < 8; ++m)
#pragma unroll
    for (int r = 0; r < 4; ++r) {
      const int row = crow + m * 16 + r;
      const float sxv = sx[row];
#pragma unroll
      for (int n = 0; n < 4; ++n)
        C[(size_t)row * N_ + ccol + n * 16] = (float)acc[m][n][r] * sxv * swv[n];
    }
}

// ---------------------------------------------------------------------------
// Fallback (ws too small): fp32 tiled GEMM with on-the-fly dequant
// ---------------------------------------------------------------------------
__global__ __launch_bounds__(256) void fallback_kernel(
    const float* __restrict__ x, const float* __restrict__ cb,
    const float* __restrict__ scales, const int* __restrict__ idx,
    const int* __restrict__ signs, float* __restrict__ out)
{
  __shared__ float Xs[32][33];
  __shared__ float Ws[32][33];
  const int t = threadIdx.x;
  const int tx = t & 31, ty = t >> 5;
  const int brow = blockIdx.y * 32, bcol = blockIdx.x * 32;
  float acc[4] = {0.f, 0.f, 0.f, 0.f};

  for (int k0 = 0; k0 < K_; k0 += 32) {
    for (int l = t; l < 1024; l += 256) {
      const int r = l >> 5, c = l & 31;
      Xs[r][c] = x[(size_t)(brow + r) * K_ + k0 + c];
      const int n = bcol + r;
      const size_t flat = (size_t)n * K_ + (k0 + c);
      const int g = (int)(flat >> 3), j = (int)(flat & 7);
      float wv = cb[idx[g] * 8 + j] * scales[n];
      if (!((signs[g] >> (7 - j)) & 1)) wv = -wv;
      Ws[r][c] = wv;
    }
    __syncthreads();
#pragma unroll
    for (int kk = 0; kk < 32; ++kk) {
      const float wv = Ws[tx][kk];
      acc[0] += Xs[ty][kk] * wv;
      acc[1] += Xs[ty + 8][kk] * wv;
      acc[2] += Xs[ty + 16][kk] * wv;
      acc[3] += Xs[ty + 24][kk] * wv;
    }
    __syncthreads();
  }
#pragma unroll
  for (int q = 0; q < 4; ++q)
    out[(size_t)(brow + ty + 8 * q) * N_ + bcol + tx] = acc[q];
}

// ---------------------------------------------------------------------------
extern "C" void kernel_launch(void* const* d_in, const int* in_sizes, int n_in,
                              void* d_out, int out_size, void* d_ws, size_t ws_size,
                              hipStream_t stream)
{
  const float* x      = (const float*)d_in[0];
  const float* cb     = (const float*)d_in[1];
  const float* scales = (const float*)d_in[2];
  const int*   idx    = (const int*)d_in[3];
  const int*   signs  = (const int*)d_in[4];
  float* out = (float*)d_out;

  const size_t wq = (size_t)N_ * K_;        // 16.8 MB i8
  const size_t xq = (size_t)M_ * K_;        // 33.6 MB i8
  const size_t need = wq + xq + (N_ + M_) * sizeof(float);

  if (ws_size >= need) {
    signed char* Wq = (signed char*)d_ws;
    signed char* Xq = Wq + wq;
    float* swp = (float*)(Xq + xq);
    float* sxp = swp + N_;
    prep_kernel<<<N_ + M_, 256, 0, stream>>>(x, cb, scales, idx, signs, Wq, Xq, swp, sxp);
    gemmq_kernel<<<(M_ / BM) * (N_ / BN), 512, 0, stream>>>(Xq, Wq, sxp, swp, out);
  } else {
    fallback_kernel<<<dim3(N_ / 32, M_ / 32), 256, 0, stream>>>(x, cb, scales, idx, signs, out);
  }
}